// Round 4
// baseline (282.783 us; speedup 1.0000x reference)
//
#include <hip/hip_runtime.h>

typedef _Float16 half8_t __attribute__((ext_vector_type(8)));
typedef __fp16   fp16x2_t __attribute__((ext_vector_type(2)));
typedef float    f32x4_t __attribute__((ext_vector_type(4)));

static constexpr int BATCH = 2048;
static constexpr int NSEQ  = BATCH * 64;   // 131072 sequences
static constexpr int VOCABN = 10000;
static constexpr float L2E = 1.44269504f;

__device__ __forceinline__ float sig2(float z, float bp) {
    float e = __builtin_amdgcn_exp2f(fmaf(z, -L2E, bp));
    return __builtin_amdgcn_rcpf(1.f + e);
}
__device__ __forceinline__ float th2(float z, float bp) {
    float e = __builtin_amdgcn_exp2f(fmaf(z, 2.f * L2E, bp));
    return fmaf(-2.f, __builtin_amdgcn_rcpf(1.f + e), 1.f);
}
__device__ __forceinline__ float tanh1(float z) {
    float e = __builtin_amdgcn_exp2f(z * (2.f * L2E));
    return fmaf(-2.f, __builtin_amdgcn_rcpf(1.f + e), 1.f);
}

__global__ __launch_bounds__(256) void conv_emb(const float* __restrict__ emb,
                                                _Float16* __restrict__ e16) {
    int i = blockIdx.x * 256 + threadIdx.x;
    if (i < VOCABN * 32) e16[i] = (_Float16)emb[i];
}

// Pack Wr / Wk into MFMA B-fragment order (f16). B-frag (16x16x32): lane l
// holds B[k][col = blk*16 + (l&15)], k = (l>>4)*8 + j. Wr uses permuted
// k' = 2*(u&15) + (u>>4) so h can be packed as cvt_pkrtz(h[u], h[u+16]).
__global__ __launch_bounds__(128) void prep_frags(const float* __restrict__ Wr,
                                                  const float* __restrict__ Wk,
                                                  ushort* __restrict__ fwr,
                                                  ushort* __restrict__ fwk) {
    const int lane = threadIdx.x & 63;
    const bool isWk = threadIdx.x >= 64;
    const float* W = isWk ? Wk : Wr;
    ushort* dst = isWk ? fwk : fwr;
    #pragma unroll
    for (int b = 0; b < 8; ++b) {
        #pragma unroll
        for (int j = 0; j < 8; ++j) {
            int kk = (lane >> 4) * 8 + j;
            int krow = isWk ? kk : ((kk >> 1) + 16 * (kk & 1));
            int col = b * 16 + (lane & 15);
            _Float16 v = (_Float16)W[krow * 128 + col];
            dst[(b * 64 + lane) * 8 + j] = __builtin_bit_cast(ushort, v);
        }
    }
}

// ---------------------------------------------------------------------------
// Bidirectional LSTM, fw+bw fused in one MFMA: A rows 0-7 = forward of 8
// seqs (token s), rows 8-15 = backward of the same seqs (token 15-s).
// Critical chain per step = ds_read(h) -> ONE mfma(h,Wr,acc_prestaged) ->
// gates -> ds_write(h). The e@Wk part for step s+1 is prestaged into acc at
// the end of step s (depends only on prefetched embeddings).
// ---------------------------------------------------------------------------
__global__ __launch_bounds__(256) void lstm_mfma(const int* __restrict__ x,
                                                 const ushort* __restrict__ fwr,
                                                 const ushort* __restrict__ fwk,
                                                 const float* __restrict__ bias,
                                                 const _Float16* __restrict__ e16,
                                                 float* __restrict__ state) {
    __shared__ int toks[16][32];                 // [t][seq-in-block]
    __shared__ unsigned int hx[4][2][16 * 20];   // per-wave double-buffered h

    const int tid = threadIdx.x, lane = tid & 63, wid = tid >> 6;
    const int i15 = lane & 15, grp = lane >> 4;
    const long blkSeq = (long)blockIdx.x * 32;

    if (tid < 128) {   // stage 32 seqs x 16 tokens, transposed
        int s = tid >> 2, t4 = (tid & 3) * 4;
        int4 v = *(const int4*)(x + (blkSeq + s) * 16 + t4);
        toks[t4 + 0][s] = v.x; toks[t4 + 1][s] = v.y;
        toks[t4 + 2][s] = v.z; toks[t4 + 3][s] = v.w;
    }

    const half8_t* fwr8 = (const half8_t*)fwr;
    const half8_t* fwk8 = (const half8_t*)fwk;
    half8_t Bwr[8], Bwk[8];
    #pragma unroll
    for (int b = 0; b < 8; ++b) { Bwr[b] = fwr8[b * 64 + lane]; Bwk[b] = fwk8[b * 64 + lane]; }

    float bp[8];
    #pragma unroll
    for (int b = 0; b < 8; ++b) {
        float bb = bias[b * 16 + i15];
        bp[b] = (b == 4 || b == 5) ? (2.f * L2E) * bb : (-L2E) * bb;
    }
    __syncthreads();

    const int wseq8 = wid * 8;                 // this wave's 8 sequences
    const bool ebw = i15 >= 8;                 // A-row >= 8 -> backward dir
    const int eseq = wseq8 + (i15 & 7);        // seq index for A-row i15
    const bool mbw = grp >= 2;                 // D-rows grp*4+r >= 8 -> bw
    const int mseq = wseq8 + (grp & 1) * 4;    // seq base for this grp's rows

    unsigned int* hb0 = &hx[wid][0][0];
    unsigned int* hb1 = &hx[wid][1][0];

    float hreg[4][2], creg[4][2];
    #pragma unroll
    for (int r = 0; r < 4; ++r) { hreg[r][0] = hreg[r][1] = creg[r][0] = creg[r][1] = 0.f; }

    const f32x4_t kzero = {0.f, 0.f, 0.f, 0.f};

    // prologue: acc = e(0)@Wk ; prefetch e(1)
    half8_t e0 = *(const half8_t*)(e16 + (long)toks[ebw ? 15 : 0][eseq] * 32 + grp * 8);
    f32x4_t acc[8];
    #pragma unroll
    for (int b = 0; b < 8; ++b)
        acc[b] = __builtin_amdgcn_mfma_f32_16x16x32_f16(e0, Bwk[b], kzero, 0, 0, 0);
    half8_t eb1 = *(const half8_t*)(e16 + (long)toks[ebw ? 14 : 1][eseq] * 32 + grp * 8);
    half8_t eb0 = eb1;   // init; real e(even) filled by prefetch

    #pragma unroll 2
    for (int s = 0; s < 16; ++s) {
        // (A) one h-dependent MFMA per block (acc already holds e-part + 0C)
        if (s > 0) {
            const unsigned int* rb = (s & 1) ? hb0 : hb1;   // written at s-1
            asm volatile("s_waitcnt lgkmcnt(0)" ::: "memory");
            half8_t Ah = *(const half8_t*)(rb + i15 * 20 + grp * 4);
            #pragma unroll
            for (int b = 0; b < 8; ++b)
                acc[b] = __builtin_amdgcn_mfma_f32_16x16x32_f16(Ah, Bwr[b], acc[b], 0, 0, 0);
        }
        // (B) prefetch e(s+2)
        if (s < 14) {
            const int tn = ebw ? 13 - s : s + 2;
            half8_t ld = *(const half8_t*)(e16 + (long)toks[tn][eseq] * 32 + grp * 8);
            if (s & 1) eb1 = ld; else eb0 = ld;
        }
        // (C) gates + h/c update + h pack into LDS
        const int tm = mbw ? 15 - s : s;
        unsigned int* wb = (s & 1) ? hb1 : hb0;
        #pragma unroll
        for (int r = 0; r < 4; ++r) {
            const bool m = (toks[tm][mseq + r] != 0);
            #pragma unroll
            for (int hf = 0; hf < 2; ++hf) {
                float zi = acc[0 + hf][r], zf = acc[2 + hf][r];
                float zg = acc[4 + hf][r], zo = acc[6 + hf][r];
                float ii = sig2(zi, bp[0 + hf]);
                float ff = sig2(zf, bp[2 + hf]);
                float gg = th2(zg, bp[4 + hf]);
                float oo = sig2(zo, bp[6 + hf]);
                float cn = fmaf(ff, creg[r][hf], ii * gg);
                float hn = oo * tanh1(cn);
                creg[r][hf] = m ? cn : creg[r][hf];
                hreg[r][hf] = m ? hn : hreg[r][hf];
            }
            fp16x2_t p2 = __builtin_amdgcn_cvt_pkrtz(hreg[r][0], hreg[r][1]);
            wb[(grp * 4 + r) * 20 + i15] = __builtin_bit_cast(unsigned int, p2);
        }
        // (D) prestage e(s+1)@Wk for next step (independent of h-chain)
        if (s < 15) {
            half8_t en = (s & 1) ? eb0 : eb1;   // e(s+1)
            #pragma unroll
            for (int b = 0; b < 8; ++b)
                acc[b] = __builtin_amdgcn_mfma_f32_16x16x32_f16(en, Bwk[b], kzero, 0, 0, 0);
        }
    }

    #pragma unroll
    for (int r = 0; r < 4; ++r)
        #pragma unroll
        for (int hf = 0; hf < 2; ++hf)
            state[(blkSeq + mseq + r) * 64 + (grp >> 1) * 32 + hf * 16 + i15] = hreg[r][hf];
}

// ---------------------------------------------------------------------------
// Projection: 8 batch rows per block (halves Wd L2 re-read traffic vs 4).
// ---------------------------------------------------------------------------
__global__ __launch_bounds__(256) void proj_kernel(const float* __restrict__ state,
                                                   const float* __restrict__ Wd,
                                                   const float* __restrict__ bd,
                                                   float* __restrict__ out) {
    __shared__ float red[4][8][64];
    const int tid = threadIdx.x;
    const int o  = tid & 63;
    const int qg = tid >> 6;
    const int b0 = blockIdx.x * 8;
    float acc[8];
    #pragma unroll
    for (int r = 0; r < 8; ++r) acc[r] = 0.f;
    const float4* sv = (const float4*)state;
    #pragma unroll 2
    for (int qq = 0; qq < 256; ++qq) {
        const int q = qg * 1024 + qq * 4;
        const float w0 = Wd[(q + 0) * 64 + o];
        const float w1 = Wd[(q + 1) * 64 + o];
        const float w2 = Wd[(q + 2) * 64 + o];
        const float w3 = Wd[(q + 3) * 64 + o];
        #pragma unroll
        for (int r = 0; r < 8; ++r) {
            const float4 s = sv[((b0 + r) * 4096 + q) >> 2];
            acc[r] = fmaf(s.x, w0, fmaf(s.y, w1, fmaf(s.z, w2, fmaf(s.w, w3, acc[r]))));
        }
    }
    #pragma unroll
    for (int r = 0; r < 8; ++r) red[qg][r][o] = acc[r];
    __syncthreads();
    #pragma unroll
    for (int i = tid; i < 512; i += 256) {
        const int r = i >> 6, oc = i & 63;
        const float v = red[0][r][oc] + red[1][r][oc] + red[2][r][oc] + red[3][r][oc] + bd[oc];
        out[(b0 + r) * 64 + oc] = tanh1(v);
    }
}

extern "C" void kernel_launch(void* const* d_in, const int* in_sizes, int n_in,
                              void* d_out, int out_size, void* d_ws, size_t ws_size,
                              hipStream_t stream) {
    const int*   x    = (const int*)d_in[0];
    const float* emb  = (const float*)d_in[1];
    const float* Wk   = (const float*)d_in[2];
    const float* Wr   = (const float*)d_in[3];
    const float* bias = (const float*)d_in[4];
    const float* Wd   = (const float*)d_in[5];
    const float* bd   = (const float*)d_in[6];
    float* out = (float*)d_out;

    float*    state = (float*)d_ws;                               // 33,554,432 B
    _Float16* e16   = (_Float16*)((char*)d_ws + 33554432);        //    640,000 B
    ushort*   fwr   = (ushort*)((char*)d_ws + 34194432);          //      8,192 B
    ushort*   fwk   = fwr + 4096;                                 //      8,192 B

    conv_emb<<<(VOCABN * 32 + 255) / 256, 256, 0, stream>>>(emb, e16);
    prep_frags<<<1, 128, 0, stream>>>(Wr, Wk, fwr, fwk);
    lstm_mfma<<<NSEQ / 32, 256, 0, stream>>>(x, fwr, fwk, bias, e16, state);
    proj_kernel<<<BATCH / 8, 256, 0, stream>>>(state, Wd, bd, out);
}

// Round 5
// 265.255 us; speedup vs baseline: 1.0661x; 1.0661x over previous
//
#include <hip/hip_runtime.h>

typedef _Float16 half8_t __attribute__((ext_vector_type(8)));
typedef __fp16   fp16x2_t __attribute__((ext_vector_type(2)));
typedef float    f32x4_t __attribute__((ext_vector_type(4)));

static constexpr int BATCH = 2048;
static constexpr int NSEQ  = BATCH * 64;   // 131072 sequences
static constexpr int VOCABN = 10000;
static constexpr float L2E = 1.44269504f;

__device__ __forceinline__ float sig2(float z, float bp) {
    float e = __builtin_amdgcn_exp2f(fmaf(z, -L2E, bp));
    return __builtin_amdgcn_rcpf(1.f + e);
}
__device__ __forceinline__ float th2(float z, float bp) {
    float e = __builtin_amdgcn_exp2f(fmaf(z, 2.f * L2E, bp));
    return fmaf(-2.f, __builtin_amdgcn_rcpf(1.f + e), 1.f);
}
__device__ __forceinline__ float tanh1(float z) {
    float e = __builtin_amdgcn_exp2f(z * (2.f * L2E));
    return fmaf(-2.f, __builtin_amdgcn_rcpf(1.f + e), 1.f);
}

__global__ __launch_bounds__(256) void conv_emb(const float* __restrict__ emb,
                                                _Float16* __restrict__ e16) {
    int i = blockIdx.x * 256 + threadIdx.x;
    if (i < VOCABN * 32) e16[i] = (_Float16)emb[i];
}

// Pack Wr / Wk into MFMA B-fragment order (f16). B-frag (16x16x32): lane l
// holds B[k][col = blk*16 + (l&15)], k = (l>>4)*8 + j. Wr uses permuted
// k' = 2*(u&15) + (u>>4) so h can be packed as cvt_pkrtz(h[u], h[u+16]).
__global__ __launch_bounds__(128) void prep_frags(const float* __restrict__ Wr,
                                                  const float* __restrict__ Wk,
                                                  ushort* __restrict__ fwr,
                                                  ushort* __restrict__ fwk) {
    const int lane = threadIdx.x & 63;
    const bool isWk = threadIdx.x >= 64;
    const float* W = isWk ? Wk : Wr;
    ushort* dst = isWk ? fwk : fwr;
    #pragma unroll
    for (int b = 0; b < 8; ++b) {
        #pragma unroll
        for (int j = 0; j < 8; ++j) {
            int kk = (lane >> 4) * 8 + j;
            int krow = isWk ? kk : ((kk >> 1) + 16 * (kk & 1));
            int col = b * 16 + (lane & 15);
            _Float16 v = (_Float16)W[krow * 128 + col];
            dst[(b * 64 + lane) * 8 + j] = __builtin_bit_cast(ushort, v);
        }
    }
}

// Pack Wd [4096][64] into B-fragments for the projection GEMM (f16).
// fwd[(ks*4+blk)*512 + lane*8 + j] = Wd[ks*32 + (lane>>4)*8 + j][blk*16 + (lane&15)]
__global__ __launch_bounds__(256) void prep_wd(const float* __restrict__ Wd,
                                               ushort* __restrict__ fwd) {
    const int idx = blockIdx.x * 256 + threadIdx.x;   // 0..32767
    const int lane = idx & 63, ksblk = idx >> 6;
    const int ks = ksblk >> 2, blk = ksblk & 3;
    #pragma unroll
    for (int j = 0; j < 8; ++j) {
        const int k = ks * 32 + (lane >> 4) * 8 + j;
        const int col = blk * 16 + (lane & 15);
        _Float16 v = (_Float16)Wd[k * 64 + col];
        fwd[ksblk * 512 + lane * 8 + j] = __builtin_bit_cast(ushort, v);
    }
}

// ---------------------------------------------------------------------------
// Bidirectional LSTM, fw+bw fused in one MFMA (A rows 0-7 fw / 8-15 bw of the
// same 8 seqs). Incremental index registers for all per-step LDS reads;
// h transposed through per-wave double-buffered LDS (stride-20 u32 rows).
// State written as f16 for the MFMA projection.
// ---------------------------------------------------------------------------
__global__ __launch_bounds__(256) void lstm_mfma(const int* __restrict__ x,
                                                 const ushort* __restrict__ fwr,
                                                 const ushort* __restrict__ fwk,
                                                 const float* __restrict__ bias,
                                                 const _Float16* __restrict__ e16,
                                                 ushort* __restrict__ state16) {
    __shared__ int toks[16 * 32];                // [t][seq-in-block]
    __shared__ unsigned int hx[4][2][16 * 20];   // per-wave double-buffered h

    const int tid = threadIdx.x, lane = tid & 63, wid = tid >> 6;
    const int i15 = lane & 15, grp = lane >> 4;
    const long blkSeq = (long)blockIdx.x * 32;

    if (tid < 128) {   // stage 32 seqs x 16 tokens, transposed
        int s = tid >> 2, t4 = (tid & 3) * 4;
        int4 v = *(const int4*)(x + (blkSeq + s) * 16 + t4);
        toks[(t4 + 0) * 32 + s] = v.x; toks[(t4 + 1) * 32 + s] = v.y;
        toks[(t4 + 2) * 32 + s] = v.z; toks[(t4 + 3) * 32 + s] = v.w;
    }

    const half8_t* fwr8 = (const half8_t*)fwr;
    const half8_t* fwk8 = (const half8_t*)fwk;
    half8_t Bwr[8], Bwk[8];
    #pragma unroll
    for (int b = 0; b < 8; ++b) { Bwr[b] = fwr8[b * 64 + lane]; Bwk[b] = fwk8[b * 64 + lane]; }

    float bp[8];
    #pragma unroll
    for (int b = 0; b < 8; ++b) {
        float bb = bias[b * 16 + i15];
        bp[b] = (b == 4 || b == 5) ? (2.f * L2E) * bb : (-L2E) * bb;
    }
    __syncthreads();

    const int wseq8 = wid * 8;
    const bool ebw = i15 >= 8;                 // A-row >= 8 -> backward dir
    const int eseq = wseq8 + (i15 & 7);
    const bool mbw = grp >= 2;                 // D-rows grp*4+r >= 8 -> bw
    const int mseq = wseq8 + (grp & 1) * 4;

    // incremental LDS indices (int elements)
    int idxm = (mbw ? 15 * 32 : 0) + mseq;     const int dm = mbw ? -32 : 32;
    int idxe = (ebw ? 13 * 32 : 2 * 32) + eseq; const int de = ebw ? -32 : 32;

    unsigned int* hb0 = &hx[wid][0][0];
    unsigned int* hb1 = &hx[wid][1][0];
    const unsigned int* rp0 = hb0 + i15 * 20 + grp * 4;   // read bases
    const unsigned int* rp1 = hb1 + i15 * 20 + grp * 4;
    unsigned int* wp0 = hb0 + grp * 80 + i15;             // write bases (+r*20)
    unsigned int* wp1 = hb1 + grp * 80 + i15;

    float hreg[4][2], creg[4][2];
    #pragma unroll
    for (int r = 0; r < 4; ++r) { hreg[r][0] = hreg[r][1] = creg[r][0] = creg[r][1] = 0.f; }

    const f32x4_t kzero = {0.f, 0.f, 0.f, 0.f};

    // prologue: acc = e(0)@Wk ; prefetch e(1)
    half8_t e0 = *(const half8_t*)(e16 + (long)toks[(ebw ? 15 * 32 : 0) + eseq] * 32 + grp * 8);
    f32x4_t acc[8];
    #pragma unroll
    for (int b = 0; b < 8; ++b)
        acc[b] = __builtin_amdgcn_mfma_f32_16x16x32_f16(e0, Bwk[b], kzero, 0, 0, 0);
    half8_t eb1 = *(const half8_t*)(e16 + (long)toks[(ebw ? 14 * 32 : 32) + eseq] * 32 + grp * 8);
    half8_t eb0 = eb1;   // dummy; real e(even) filled by prefetch

    #pragma unroll 2
    for (int s = 0; s < 16; ++s) {
        // (A) one h-dependent MFMA set (acc already holds e-part)
        if (s > 0) {
            const unsigned int* rb = (s & 1) ? rp0 : rp1;   // written at s-1
            asm volatile("s_waitcnt lgkmcnt(0)" ::: "memory");
            half8_t Ah = *(const half8_t*)rb;
            #pragma unroll
            for (int b = 0; b < 8; ++b)
                acc[b] = __builtin_amdgcn_mfma_f32_16x16x32_f16(Ah, Bwr[b], acc[b], 0, 0, 0);
        }
        // (B) prefetch e(s+2)
        if (s < 14) {
            int tokn = toks[idxe];
            half8_t ld = *(const half8_t*)(e16 + (long)tokn * 32 + grp * 8);
            if (s & 1) eb1 = ld; else eb0 = ld;
        }
        idxe += de;
        // (C) gates + h/c update + h pack into LDS
        unsigned int* wb = (s & 1) ? wp1 : wp0;
        int mt0 = toks[idxm + 0], mt1 = toks[idxm + 1];
        int mt2 = toks[idxm + 2], mt3 = toks[idxm + 3];
        idxm += dm;
        int mts[4] = {mt0, mt1, mt2, mt3};
        #pragma unroll
        for (int r = 0; r < 4; ++r) {
            const bool m = (mts[r] != 0);
            #pragma unroll
            for (int hf = 0; hf < 2; ++hf) {
                float zi = acc[0 + hf][r], zf = acc[2 + hf][r];
                float zg = acc[4 + hf][r], zo = acc[6 + hf][r];
                float ii = sig2(zi, bp[0 + hf]);
                float ff = sig2(zf, bp[2 + hf]);
                float gg = th2(zg, bp[4 + hf]);
                float oo = sig2(zo, bp[6 + hf]);
                float cn = fmaf(ff, creg[r][hf], ii * gg);
                float hn = oo * tanh1(cn);
                creg[r][hf] = m ? cn : creg[r][hf];
                hreg[r][hf] = m ? hn : hreg[r][hf];
            }
            fp16x2_t p2 = __builtin_amdgcn_cvt_pkrtz(hreg[r][0], hreg[r][1]);
            wb[r * 20] = __builtin_bit_cast(unsigned int, p2);
        }
        // (D) prestage e(s+1)@Wk for next step (independent of h-chain)
        if (s < 15) {
            half8_t en = (s & 1) ? eb0 : eb1;   // e(s+1)
            #pragma unroll
            for (int b = 0; b < 8; ++b)
                acc[b] = __builtin_amdgcn_mfma_f32_16x16x32_f16(en, Bwk[b], kzero, 0, 0, 0);
        }
    }

    #pragma unroll
    for (int r = 0; r < 4; ++r)
        #pragma unroll
        for (int hf = 0; hf < 2; ++hf) {
            _Float16 hv = (_Float16)hreg[r][hf];
            state16[(blkSeq + mseq + r) * 64 + (grp >> 1) * 32 + hf * 16 + i15] =
                __builtin_bit_cast(ushort, hv);
        }
}

// ---------------------------------------------------------------------------
// Projection as MFMA GEMM: out[2048][64] = tanh(state16[2048][4096] @ Wd + bd)
// One wave per 16 batch rows; K=4096 in 128 steps of 32; bias via C-init.
// ---------------------------------------------------------------------------
__global__ __launch_bounds__(64) void proj_mfma(const ushort* __restrict__ state16,
                                                const ushort* __restrict__ fwd,
                                                const float* __restrict__ bd,
                                                float* __restrict__ out) {
    const int lane = threadIdx.x;
    const int i15 = lane & 15, grp = lane >> 4;
    const int r0 = blockIdx.x * 16;

    const half8_t* fw8 = (const half8_t*)fwd;
    const half8_t* sa  = (const half8_t*)state16;

    f32x4_t acc[4];
    #pragma unroll
    for (int blk = 0; blk < 4; ++blk) {
        float c = bd[blk * 16 + i15];
        acc[blk] = (f32x4_t){c, c, c, c};
    }

    const int abase = (r0 + i15) * 512 + grp;   // half8 index into state16
    #pragma unroll 4
    for (int ks = 0; ks < 128; ++ks) {
        half8_t A = sa[abase + ks * 4];
        #pragma unroll
        for (int blk = 0; blk < 4; ++blk)
            acc[blk] = __builtin_amdgcn_mfma_f32_16x16x32_f16(A, fw8[(ks * 4 + blk) * 64 + lane],
                                                              acc[blk], 0, 0, 0);
    }

    #pragma unroll
    for (int blk = 0; blk < 4; ++blk)
        #pragma unroll
        for (int q = 0; q < 4; ++q)
            out[(r0 + grp * 4 + q) * 64 + blk * 16 + i15] = tanh1(acc[blk][q]);
}

extern "C" void kernel_launch(void* const* d_in, const int* in_sizes, int n_in,
                              void* d_out, int out_size, void* d_ws, size_t ws_size,
                              hipStream_t stream) {
    const int*   x    = (const int*)d_in[0];
    const float* emb  = (const float*)d_in[1];
    const float* Wk   = (const float*)d_in[2];
    const float* Wr   = (const float*)d_in[3];
    const float* bias = (const float*)d_in[4];
    const float* Wd   = (const float*)d_in[5];
    const float* bd   = (const float*)d_in[6];
    float* out = (float*)d_out;

    ushort*   state16 = (ushort*)d_ws;                            // 16,777,216 B
    _Float16* e16     = (_Float16*)((char*)d_ws + 16777216);      //    640,000 B
    ushort*   fwr     = (ushort*)((char*)d_ws + 17417216);        //      8,192 B
    ushort*   fwk     = (ushort*)((char*)d_ws + 17425408);        //      8,192 B
    ushort*   fwd     = (ushort*)((char*)d_ws + 17433600);        //    524,288 B

    conv_emb<<<(VOCABN * 32 + 255) / 256, 256, 0, stream>>>(emb, e16);
    prep_frags<<<1, 128, 0, stream>>>(Wr, Wk, fwr, fwk);
    prep_wd<<<128, 256, 0, stream>>>(Wd, fwd);
    lstm_mfma<<<NSEQ / 32, 256, 0, stream>>>(x, fwr, fwk, bias, e16, state16);
    proj_mfma<<<BATCH / 16, 64, 0, stream>>>(state16, fwd, bd, out);
}

// Round 8
// 260.145 us; speedup vs baseline: 1.0870x; 1.0196x over previous
//
#include <hip/hip_runtime.h>

typedef _Float16 half8_t __attribute__((ext_vector_type(8)));
typedef __fp16   fp16x2_t __attribute__((ext_vector_type(2)));
typedef float    f32x4_t __attribute__((ext_vector_type(4)));

static constexpr int BATCH = 2048;
static constexpr int NSEQ  = BATCH * 64;   // 131072 sequences
static constexpr int VOCABN = 10000;
static constexpr float L2E = 1.44269504f;

__device__ __forceinline__ float sig2(float z, float bp) {
    float e = __builtin_amdgcn_exp2f(fmaf(z, -L2E, bp));
    return __builtin_amdgcn_rcpf(1.f + e);
}
__device__ __forceinline__ float th2(float z, float bp) {
    float e = __builtin_amdgcn_exp2f(fmaf(z, 2.f * L2E, bp));
    return fmaf(-2.f, __builtin_amdgcn_rcpf(1.f + e), 1.f);
}
__device__ __forceinline__ float tanh1(float z) {
    float e = __builtin_amdgcn_exp2f(z * (2.f * L2E));
    return fmaf(-2.f, __builtin_amdgcn_rcpf(1.f + e), 1.f);
}

// ---------------------------------------------------------------------------
// Fused prep: [0,1250) emb->f16 | [1250,1266) Wr/Wk B-frags | [1266,1394) Wd
// Each sub-range reproduces the round-5 proven kernels' math exactly.
// ---------------------------------------------------------------------------
__global__ __launch_bounds__(256) void prep_all(const float* __restrict__ emb,
                                                const float* __restrict__ Wr,
                                                const float* __restrict__ Wk,
                                                const float* __restrict__ Wd,
                                                _Float16* __restrict__ e16,
                                                ushort* __restrict__ fwr,
                                                ushort* __restrict__ fwk,
                                                ushort* __restrict__ fwd) {
    const int bid = blockIdx.x, tid = threadIdx.x;
    if (bid < 1250) {                       // embedding f32 -> f16
        int i = bid * 256 + tid;
        if (i < VOCABN * 32) e16[i] = (_Float16)emb[i];
    } else if (bid < 1266) {                // Wr / Wk B-fragments
        if (tid >= 64) return;
        const int lane = tid;
        const int b16 = bid - 1250;
        const int kind = b16 >> 3, b = b16 & 7;
        const float* W = kind ? Wk : Wr;
        ushort* dst = kind ? fwk : fwr;
        #pragma unroll
        for (int j = 0; j < 8; ++j) {
            int kk = (lane >> 4) * 8 + j;
            int krow = kind ? kk : ((kk >> 1) + 16 * (kk & 1));   // Wr k-permuted
            int col = b * 16 + (lane & 15);
            _Float16 v = (_Float16)W[krow * 128 + col];
            dst[(b * 64 + lane) * 8 + j] = __builtin_bit_cast(ushort, v);
        }
    } else {                                // Wd B-fragments
        const int idx = (bid - 1266) * 256 + tid;   // 0..32767
        const int lane = idx & 63, ksblk = idx >> 6;
        const int ks = ksblk >> 2, blk = ksblk & 3;
        #pragma unroll
        for (int j = 0; j < 8; ++j) {
            const int k = ks * 32 + (lane >> 4) * 8 + j;
            const int col = blk * 16 + (lane & 15);
            _Float16 v = (_Float16)Wd[k * 64 + col];
            fwd[ksblk * 512 + lane * 8 + j] = __builtin_bit_cast(ushort, v);
        }
    }
}

// ---------------------------------------------------------------------------
// Bidirectional LSTM (round-5 kernel + rule-18 sched_barrier fence).
// ---------------------------------------------------------------------------
__global__ __launch_bounds__(256) void lstm_mfma(const int* __restrict__ x,
                                                 const ushort* __restrict__ fwr,
                                                 const ushort* __restrict__ fwk,
                                                 const float* __restrict__ bias,
                                                 const _Float16* __restrict__ e16,
                                                 ushort* __restrict__ state16) {
    __shared__ int toks[16 * 32];                // [t][seq-in-block]
    __shared__ unsigned int hx[4][2][16 * 20];   // per-wave double-buffered h

    const int tid = threadIdx.x, lane = tid & 63, wid = tid >> 6;
    const int i15 = lane & 15, grp = lane >> 4;
    const long blkSeq = (long)blockIdx.x * 32;

    if (tid < 128) {   // stage 32 seqs x 16 tokens, transposed
        int s = tid >> 2, t4 = (tid & 3) * 4;
        int4 v = *(const int4*)(x + (blkSeq + s) * 16 + t4);
        toks[(t4 + 0) * 32 + s] = v.x; toks[(t4 + 1) * 32 + s] = v.y;
        toks[(t4 + 2) * 32 + s] = v.z; toks[(t4 + 3) * 32 + s] = v.w;
    }

    const half8_t* fwr8 = (const half8_t*)fwr;
    const half8_t* fwk8 = (const half8_t*)fwk;
    half8_t Bwr[8], Bwk[8];
    #pragma unroll
    for (int b = 0; b < 8; ++b) { Bwr[b] = fwr8[b * 64 + lane]; Bwk[b] = fwk8[b * 64 + lane]; }

    float bp[8];
    #pragma unroll
    for (int b = 0; b < 8; ++b) {
        float bb = bias[b * 16 + i15];
        bp[b] = (b == 4 || b == 5) ? (2.f * L2E) * bb : (-L2E) * bb;
    }
    __syncthreads();

    const int wseq8 = wid * 8;
    const bool ebw = i15 >= 8;                 // A-row >= 8 -> backward dir
    const int eseq = wseq8 + (i15 & 7);
    const bool mbw = grp >= 2;                 // D-rows grp*4+r >= 8 -> bw
    const int mseq = wseq8 + (grp & 1) * 4;

    // incremental LDS indices (int elements)
    int idxm = (mbw ? 15 * 32 : 0) + mseq;     const int dm = mbw ? -32 : 32;
    int idxe = (ebw ? 13 * 32 : 2 * 32) + eseq; const int de = ebw ? -32 : 32;

    unsigned int* hb0 = &hx[wid][0][0];
    unsigned int* hb1 = &hx[wid][1][0];
    const unsigned int* rp0 = hb0 + i15 * 20 + grp * 4;   // read bases
    const unsigned int* rp1 = hb1 + i15 * 20 + grp * 4;
    unsigned int* wp0 = hb0 + grp * 80 + i15;             // write bases (+r*20)
    unsigned int* wp1 = hb1 + grp * 80 + i15;

    float hreg[4][2], creg[4][2];
    #pragma unroll
    for (int r = 0; r < 4; ++r) { hreg[r][0] = hreg[r][1] = creg[r][0] = creg[r][1] = 0.f; }

    const f32x4_t kzero = {0.f, 0.f, 0.f, 0.f};

    // prologue: acc = e(0)@Wk ; prefetch e(1)
    half8_t e0 = *(const half8_t*)(e16 + (long)toks[(ebw ? 15 * 32 : 0) + eseq] * 32 + grp * 8);
    f32x4_t acc[8];
    #pragma unroll
    for (int b = 0; b < 8; ++b)
        acc[b] = __builtin_amdgcn_mfma_f32_16x16x32_f16(e0, Bwk[b], kzero, 0, 0, 0);
    half8_t eb1 = *(const half8_t*)(e16 + (long)toks[(ebw ? 14 * 32 : 32) + eseq] * 32 + grp * 8);
    half8_t eb0 = eb1;   // dummy; real e(even) filled by prefetch

    #pragma unroll 2
    for (int s = 0; s < 16; ++s) {
        // (A) one h-dependent MFMA set (acc already holds e-part)
        if (s > 0) {
            const unsigned int* rb = (s & 1) ? rp0 : rp1;   // written at s-1
            asm volatile("s_waitcnt lgkmcnt(0)" ::: "memory");
            __builtin_amdgcn_sched_barrier(0);              // rule-18 fence
            half8_t Ah = *(const half8_t*)rb;
            #pragma unroll
            for (int b = 0; b < 8; ++b)
                acc[b] = __builtin_amdgcn_mfma_f32_16x16x32_f16(Ah, Bwr[b], acc[b], 0, 0, 0);
        }
        // (B) prefetch e(s+2)
        if (s < 14) {
            int tokn = toks[idxe];
            half8_t ld = *(const half8_t*)(e16 + (long)tokn * 32 + grp * 8);
            if (s & 1) eb1 = ld; else eb0 = ld;
        }
        idxe += de;
        // (C) gates + h/c update + h pack into LDS
        unsigned int* wb = (s & 1) ? wp1 : wp0;
        int mt0 = toks[idxm + 0], mt1 = toks[idxm + 1];
        int mt2 = toks[idxm + 2], mt3 = toks[idxm + 3];
        idxm += dm;
        int mts[4] = {mt0, mt1, mt2, mt3};
        #pragma unroll
        for (int r = 0; r < 4; ++r) {
            const bool m = (mts[r] != 0);
            #pragma unroll
            for (int hf = 0; hf < 2; ++hf) {
                float zi = acc[0 + hf][r], zf = acc[2 + hf][r];
                float zg = acc[4 + hf][r], zo = acc[6 + hf][r];
                float ii = sig2(zi, bp[0 + hf]);
                float ff = sig2(zf, bp[2 + hf]);
                float gg = th2(zg, bp[4 + hf]);
                float oo = sig2(zo, bp[6 + hf]);
                float cn = fmaf(ff, creg[r][hf], ii * gg);
                float hn = oo * tanh1(cn);
                creg[r][hf] = m ? cn : creg[r][hf];
                hreg[r][hf] = m ? hn : hreg[r][hf];
            }
            fp16x2_t p2 = __builtin_amdgcn_cvt_pkrtz(hreg[r][0], hreg[r][1]);
            wb[r * 20] = __builtin_bit_cast(unsigned int, p2);
        }
        // (D) prestage e(s+1)@Wk for next step (independent of h-chain)
        if (s < 15) {
            half8_t en = (s & 1) ? eb0 : eb1;   // e(s+1)
            #pragma unroll
            for (int b = 0; b < 8; ++b)
                acc[b] = __builtin_amdgcn_mfma_f32_16x16x32_f16(en, Bwk[b], kzero, 0, 0, 0);
        }
    }

    #pragma unroll
    for (int r = 0; r < 4; ++r)
        #pragma unroll
        for (int hf = 0; hf < 2; ++hf) {
            _Float16 hv = (_Float16)hreg[r][hf];
            state16[(blkSeq + mseq + r) * 64 + (grp >> 1) * 32 + hf * 16 + i15] =
                __builtin_bit_cast(ushort, hv);
        }
}

// ---------------------------------------------------------------------------
// Projection as MFMA GEMM (VERBATIM round-5 proven kernel):
// out[2048][64] = tanh(state16[2048][4096] @ Wd + bd).
// One wave per 16 batch rows; K=4096 in 128 steps of 32; bias via C-init.
// ---------------------------------------------------------------------------
__global__ __launch_bounds__(64) void proj_mfma(const ushort* __restrict__ state16,
                                                const ushort* __restrict__ fwd,
                                                const float* __restrict__ bd,
                                                float* __restrict__ out) {
    const int lane = threadIdx.x;
    const int i15 = lane & 15, grp = lane >> 4;
    const int r0 = blockIdx.x * 16;

    const half8_t* fw8 = (const half8_t*)fwd;
    const half8_t* sa  = (const half8_t*)state16;

    f32x4_t acc[4];
    #pragma unroll
    for (int blk = 0; blk < 4; ++blk) {
        float c = bd[blk * 16 + i15];
        acc[blk] = (f32x4_t){c, c, c, c};
    }

    const int abase = (r0 + i15) * 512 + grp;   // half8 index into state16
    #pragma unroll 4
    for (int ks = 0; ks < 128; ++ks) {
        half8_t A = sa[abase + ks * 4];
        #pragma unroll
        for (int blk = 0; blk < 4; ++blk)
            acc[blk] = __builtin_amdgcn_mfma_f32_16x16x32_f16(A, fw8[(ks * 4 + blk) * 64 + lane],
                                                              acc[blk], 0, 0, 0);
    }

    #pragma unroll
    for (int blk = 0; blk < 4; ++blk)
        #pragma unroll
        for (int q = 0; q < 4; ++q)
            out[(r0 + grp * 4 + q) * 64 + blk * 16 + i15] = tanh1(acc[blk][q]);
}

extern "C" void kernel_launch(void* const* d_in, const int* in_sizes, int n_in,
                              void* d_out, int out_size, void* d_ws, size_t ws_size,
                              hipStream_t stream) {
    const int*   x    = (const int*)d_in[0];
    const float* emb  = (const float*)d_in[1];
    const float* Wk   = (const float*)d_in[2];
    const float* Wr   = (const float*)d_in[3];
    const float* bias = (const float*)d_in[4];
    const float* Wd   = (const float*)d_in[5];
    const float* bd   = (const float*)d_in[6];
    float* out = (float*)d_out;

    ushort*   state16 = (ushort*)d_ws;                            // 16,777,216 B
    _Float16* e16     = (_Float16*)((char*)d_ws + 16777216);      //    640,000 B
    ushort*   fwr     = (ushort*)((char*)d_ws + 17417216);        //      8,192 B
    ushort*   fwk     = (ushort*)((char*)d_ws + 17425408);        //      8,192 B
    ushort*   fwd     = (ushort*)((char*)d_ws + 17433600);        //    524,288 B

    prep_all<<<1394, 256, 0, stream>>>(emb, Wr, Wk, Wd, e16, fwr, fwk, fwd);
    lstm_mfma<<<NSEQ / 32, 256, 0, stream>>>(x, fwr, fwk, bias, e16, state16);
    proj_mfma<<<BATCH / 16, 64, 0, stream>>>(state16, fwd, bd, out);
}

// Round 9
// 253.501 us; speedup vs baseline: 1.1155x; 1.0262x over previous
//
#include <hip/hip_runtime.h>

typedef _Float16 half8_t __attribute__((ext_vector_type(8)));
typedef __fp16   fp16x2_t __attribute__((ext_vector_type(2)));
typedef float    f32x4_t __attribute__((ext_vector_type(4)));
typedef unsigned int u32x4_t __attribute__((ext_vector_type(4)));

static constexpr int BATCH = 2048;
static constexpr int NSEQ  = BATCH * 64;   // 131072 sequences
static constexpr int VOCABN = 10000;
static constexpr float L2E = 1.44269504f;

__device__ __forceinline__ float sigm(float z) {
    float e = __builtin_amdgcn_exp2f(z * (-L2E));
    return __builtin_amdgcn_rcpf(1.f + e);
}
__device__ __forceinline__ float tanhp(float z) {
    float e = __builtin_amdgcn_exp2f(z * (2.f * L2E));
    return fmaf(-2.f, __builtin_amdgcn_rcpf(1.f + e), 1.f);
}

// ---------------------------------------------------------------------------
// Fused prep: [0,1250) emb->f16 | [1250,1266) Wr/Wk A-frags | [1266,1394) Wd
// Fragment formula (both A and B roles): elem(lane,j) = Mat[k'][b*16+(lane&15)]
// with kk = (lane>>4)*8+j.  Wk: k'=kk (identity).  Wr: k' = sigma(kk) =
// 4*(kk>>3) + (kk&3) + 16*((kk>>2)&1)  -- chosen so each lane's gate outputs
// ARE its next-step B-fragment elements (no cross-lane movement).
// ---------------------------------------------------------------------------
__global__ __launch_bounds__(256) void prep_all(const float* __restrict__ emb,
                                                const float* __restrict__ Wr,
                                                const float* __restrict__ Wk,
                                                const float* __restrict__ Wd,
                                                _Float16* __restrict__ e16,
                                                ushort* __restrict__ fwr,
                                                ushort* __restrict__ fwk,
                                                ushort* __restrict__ fwd) {
    const int bid = blockIdx.x, tid = threadIdx.x;
    if (bid < 1250) {                       // embedding f32 -> f16
        int i = bid * 256 + tid;
        if (i < VOCABN * 32) e16[i] = (_Float16)emb[i];
    } else if (bid < 1266) {                // Wr / Wk fragments
        if (tid >= 64) return;
        const int lane = tid;
        const int b16 = bid - 1250;
        const int kind = b16 >> 3, b = b16 & 7;
        const float* W = kind ? Wk : Wr;
        ushort* dst = kind ? fwk : fwr;
        #pragma unroll
        for (int j = 0; j < 8; ++j) {
            int kk = (lane >> 4) * 8 + j;
            int krow = kind ? kk : (4 * (kk >> 3) + (kk & 3) + 16 * ((kk >> 2) & 1));
            int col = b * 16 + (lane & 15);
            _Float16 v = (_Float16)W[krow * 128 + col];
            dst[(b * 64 + lane) * 8 + j] = __builtin_bit_cast(ushort, v);
        }
    } else {                                // Wd B-fragments (proj)
        const int idx = (bid - 1266) * 256 + tid;   // 0..32767
        const int lane = idx & 63, ksblk = idx >> 6;
        const int ks = ksblk >> 2, blk = ksblk & 3;
        #pragma unroll
        for (int j = 0; j < 8; ++j) {
            const int k = ks * 32 + (lane >> 4) * 8 + j;
            const int col = blk * 16 + (lane & 15);
            _Float16 v = (_Float16)Wd[k * 64 + col];
            fwd[ksblk * 512 + lane * 8 + j] = __builtin_bit_cast(ushort, v);
        }
    }
}

// ---------------------------------------------------------------------------
// Bidirectional LSTM, swapped-operand form: z^T = Wk^T@e^T + Wr^T@h^T + b.
// A = constant weight fragments; B cols 0-7 = fw of 8 seqs, 8-15 = bw of same.
// D-layout: lane(i15,grp) holds z[col b*16+4grp+r][seq i15] -> gate math for
// units {4grp+r, 16+4grp+r} of seq i15 -> packed f16 IS next B-fragment.
// No LDS in the recurrence; bias via MFMA C-init; mask lane-uniform.
// ---------------------------------------------------------------------------
__global__ __launch_bounds__(256) void lstm_mfma(const int* __restrict__ x,
                                                 const ushort* __restrict__ fwr,
                                                 const ushort* __restrict__ fwk,
                                                 const float* __restrict__ bias,
                                                 const _Float16* __restrict__ e16,
                                                 ushort* __restrict__ state16) {
    __shared__ int toks[16 * 32];                // [t][seq-in-block]

    const int tid = threadIdx.x, lane = tid & 63, wid = tid >> 6;
    const int i15 = lane & 15, grp = lane >> 4;
    const long blkSeq = (long)blockIdx.x * 32;

    if (tid < 128) {   // stage 32 seqs x 16 tokens, transposed
        int s = tid >> 2, t4 = (tid & 3) * 4;
        int4 v = *(const int4*)(x + (blkSeq + s) * 16 + t4);
        toks[(t4 + 0) * 32 + s] = v.x; toks[(t4 + 1) * 32 + s] = v.y;
        toks[(t4 + 2) * 32 + s] = v.z; toks[(t4 + 3) * 32 + s] = v.w;
    }

    const half8_t* fwr8 = (const half8_t*)fwr;
    const half8_t* fwk8 = (const half8_t*)fwk;
    half8_t Awr[8], Awk[8];
    #pragma unroll
    for (int b = 0; b < 8; ++b) { Awr[b] = fwr8[b * 64 + lane]; Awk[b] = fwk8[b * 64 + lane]; }

    // bias C-init fragments: biasC[b][r] = bias[b*16 + 4*grp + r]
    f32x4_t biasC[8];
    #pragma unroll
    for (int b = 0; b < 8; ++b)
        biasC[b] = *(const f32x4_t*)(bias + b * 16 + grp * 4);

    __syncthreads();

    const int seqIB = wid * 8 + (i15 & 7);       // this lane's column's sequence
    const bool bw = i15 >= 8;                    // cols 8-15 run backward
    const int dstep = bw ? -32 : 32;
    int idxm = (bw ? 15 * 32 : 0) + seqIB;       // mask-token index (step s)
    int idxe = (bw ? 13 * 32 : 2 * 32) + seqIB;  // prefetch index (step s+2)

    float creg[4][2];                            // c for unit hf*16+4grp+r
    #pragma unroll
    for (int r = 0; r < 4; ++r) creg[r][0] = creg[r][1] = 0.f;
    half8_t Bh = __builtin_bit_cast(half8_t, (u32x4_t){0u, 0u, 0u, 0u});

    // prologue: acc = bias + e(0)@Wk ; prefetch e(1)
    half8_t e0 = *(const half8_t*)(e16 + (long)toks[(bw ? 15 * 32 : 0) + seqIB] * 32 + grp * 8);
    f32x4_t acc[8];
    #pragma unroll
    for (int b = 0; b < 8; ++b)
        acc[b] = __builtin_amdgcn_mfma_f32_16x16x32_f16(Awk[b], e0, biasC[b], 0, 0, 0);
    half8_t eb1 = *(const half8_t*)(e16 + (long)toks[(bw ? 14 * 32 : 32) + seqIB] * 32 + grp * 8);
    half8_t eb0 = eb1;   // dummy; real value filled by prefetch

    #pragma unroll 2
    for (int s = 0; s < 16; ++s) {
        // (A) h-recurrence MFMA: acc += Wr^T @ h^T  (Bh from previous step)
        #pragma unroll
        for (int b = 0; b < 8; ++b)
            acc[b] = __builtin_amdgcn_mfma_f32_16x16x32_f16(Awr[b], Bh, acc[b], 0, 0, 0);
        // (B) prefetch e(s+2)
        if (s < 14) {
            half8_t ld = *(const half8_t*)(e16 + (long)toks[idxe] * 32 + grp * 8);
            if (s & 1) eb1 = ld; else eb0 = ld;
        }
        idxe += dstep;
        // (C) mask + gates (all values of this lane belong to seq i15)
        const bool m = (toks[idxm] != 0);
        idxm += dstep;
        float hn[4][2];
        #pragma unroll
        for (int r = 0; r < 4; ++r) {
            #pragma unroll
            for (int hf = 0; hf < 2; ++hf) {
                float zi = acc[0 + hf][r], zf = acc[2 + hf][r];
                float zg = acc[4 + hf][r], zo = acc[6 + hf][r];
                float ii = sigm(zi);
                float ff = sigm(zf);
                float gg = tanhp(zg);
                float oo = sigm(zo);
                float cn = fmaf(ff, creg[r][hf], ii * gg);
                hn[r][hf] = oo * tanhp(cn);
                creg[r][hf] = m ? cn : creg[r][hf];
            }
        }
        // pack new h into next B-fragment (j = hf*4 + r ordering)
        fp16x2_t p0 = __builtin_amdgcn_cvt_pkrtz(hn[0][0], hn[1][0]);
        fp16x2_t p1 = __builtin_amdgcn_cvt_pkrtz(hn[2][0], hn[3][0]);
        fp16x2_t p2 = __builtin_amdgcn_cvt_pkrtz(hn[0][1], hn[1][1]);
        fp16x2_t p3 = __builtin_amdgcn_cvt_pkrtz(hn[2][1], hn[3][1]);
        u32x4_t w;
        w.x = __builtin_bit_cast(unsigned int, p0);
        w.y = __builtin_bit_cast(unsigned int, p1);
        w.z = __builtin_bit_cast(unsigned int, p2);
        w.w = __builtin_bit_cast(unsigned int, p3);
        half8_t Bh_new = __builtin_bit_cast(half8_t, w);
        Bh = m ? Bh_new : Bh;                    // packed select (4 cndmask)
        // (D) prestage bias + e(s+1)@Wk for next step
        if (s < 15) {
            half8_t en = (s & 1) ? eb0 : eb1;    // e(s+1)
            #pragma unroll
            for (int b = 0; b < 8; ++b)
                acc[b] = __builtin_amdgcn_mfma_f32_16x16x32_f16(Awk[b], en, biasC[b], 0, 0, 0);
        }
    }

    // epilogue: Bh words 0,1 = units 4grp..4grp+3 ; words 2,3 = 16+4grp..+3
    {
        u32x4_t wv = __builtin_bit_cast(u32x4_t, Bh);
        ushort* base = state16 + (blkSeq + seqIB) * 64 + (bw ? 32 : 0);
        uint2 lo = {wv.x, wv.y}, hi = {wv.z, wv.w};
        *(uint2*)(base + 4 * grp) = lo;
        *(uint2*)(base + 16 + 4 * grp) = hi;
    }
}

// ---------------------------------------------------------------------------
// Projection as MFMA GEMM (R5-proven, verbatim):
// out[2048][64] = tanh(state16[2048][4096] @ Wd + bd).
// One wave per 16 batch rows; K=4096 in 128 steps of 32; bias via C-init.
// ---------------------------------------------------------------------------
__global__ __launch_bounds__(64) void proj_mfma(const ushort* __restrict__ state16,
                                                const ushort* __restrict__ fwd,
                                                const float* __restrict__ bd,
                                                float* __restrict__ out) {
    const int lane = threadIdx.x;
    const int i15 = lane & 15, grp = lane >> 4;
    const int r0 = blockIdx.x * 16;

    const half8_t* fw8 = (const half8_t*)fwd;
    const half8_t* sa  = (const half8_t*)state16;

    f32x4_t acc[4];
    #pragma unroll
    for (int blk = 0; blk < 4; ++blk) {
        float c = bd[blk * 16 + i15];
        acc[blk] = (f32x4_t){c, c, c, c};
    }

    const int abase = (r0 + i15) * 512 + grp;   // half8 index into state16
    #pragma unroll 4
    for (int ks = 0; ks < 128; ++ks) {
        half8_t A = sa[abase + ks * 4];
        #pragma unroll
        for (int blk = 0; blk < 4; ++blk)
            acc[blk] = __builtin_amdgcn_mfma_f32_16x16x32_f16(A, fw8[(ks * 4 + blk) * 64 + lane],
                                                              acc[blk], 0, 0, 0);
    }

    #pragma unroll
    for (int blk = 0; blk < 4; ++blk)
        #pragma unroll
        for (int q = 0; q < 4; ++q) {
            float e = __builtin_amdgcn_exp2f(acc[blk][q] * (2.f * L2E));
            float t = fmaf(-2.f, __builtin_amdgcn_rcpf(1.f + e), 1.f);
            out[(r0 + grp * 4 + q) * 64 + blk * 16 + i15] = t;
        }
}

extern "C" void kernel_launch(void* const* d_in, const int* in_sizes, int n_in,
                              void* d_out, int out_size, void* d_ws, size_t ws_size,
                              hipStream_t stream) {
    const int*   x    = (const int*)d_in[0];
    const float* emb  = (const float*)d_in[1];
    const float* Wk   = (const float*)d_in[2];
    const float* Wr   = (const float*)d_in[3];
    const float* bias = (const float*)d_in[4];
    const float* Wd   = (const float*)d_in[5];
    const float* bd   = (const float*)d_in[6];
    float* out = (float*)d_out;

    ushort*   state16 = (ushort*)d_ws;                            // 16,777,216 B
    _Float16* e16     = (_Float16*)((char*)d_ws + 16777216);      //    640,000 B
    ushort*   fwr     = (ushort*)((char*)d_ws + 17417216);        //      8,192 B
    ushort*   fwk     = (ushort*)((char*)d_ws + 17425408);        //      8,192 B
    ushort*   fwd     = (ushort*)((char*)d_ws + 17433600);        //    524,288 B

    prep_all<<<1394, 256, 0, stream>>>(emb, Wr, Wk, Wd, e16, fwr, fwk, fwd);
    lstm_mfma<<<NSEQ / 32, 256, 0, stream>>>(x, fwr, fwk, bias, e16, state16);
    proj_mfma<<<BATCH / 16, 64, 0, stream>>>(state16, fwd, bd, out);
}